// Round 10
// baseline (885.921 us; speedup 1.0000x reference)
//
#include <hip/hip_runtime.h>
#include <hip/hip_bf16.h>
#include <stdint.h>

#define T_TOK 8192
#define DM 1024
#define DF 4096
#define NE 8

typedef __attribute__((ext_vector_type(8))) short short8;
typedef __attribute__((ext_vector_type(8))) unsigned short ushort8;
typedef __attribute__((ext_vector_type(4))) float f32x4;

#define AS1 __attribute__((address_space(1)))
#define AS3 __attribute__((address_space(3)))

static __device__ __forceinline__ unsigned short f2bf(float f) {
  union { float f; unsigned int u; } c; c.f = f;
  unsigned int u = c.u;
  unsigned int r = (u + 0x7FFFu + ((u >> 16) & 1u)) >> 16;
  return (unsigned short)r;
}

static __device__ __forceinline__ float gelu_tanh(float v) {
  float y = 0.7978845608028654f * (v + 0.044715f * v * v * v);
  float ay = fabsf(y);
  float e = __expf(-2.0f * ay);
  float th = (1.0f - e) / (1.0f + e);
  th = copysignf(th, y);
  return 0.5f * v * (1.0f + th);
}

__global__ void k_zero(float* out, int n, int* counts) {
  int gid = blockIdx.x * blockDim.x + threadIdx.x;
  if (gid < NE) counts[gid] = 0;
  for (int i = gid; i < n; i += gridDim.x * blockDim.x) out[i] = 0.f;
}

__global__ void k_probe(float* out, float v, int n) {
  int i = blockIdx.x * blockDim.x + threadIdx.x;
  for (; i < n; i += gridDim.x * blockDim.x) out[i] = v;
}

// Fused: bf16 conversion of x + gating (reads x once). One wave per token.
__global__ void k_prep(const float* __restrict__ x, unsigned short* __restrict__ xb,
                       const float* __restrict__ Wg, const float* __restrict__ bg,
                       int* __restrict__ counts, int* __restrict__ btok,
                       float* __restrict__ bw) {
  int wave = threadIdx.x >> 6, lane = threadIdx.x & 63;
  int t = blockIdx.x * 4 + wave;
  const float* xr = x + (size_t)t * DM;
  unsigned short* xo = xb + (size_t)t * DM;
  double acc[NE];
#pragma unroll
  for (int e = 0; e < NE; ++e) acc[e] = 0.0;
#pragma unroll
  for (int i = 0; i < 4; ++i) {
    int d = lane * 4 + i * 256;
    float4 v = *(const float4*)(xr + d);
    ushort4 o;
    o.x = f2bf(v.x); o.y = f2bf(v.y); o.z = f2bf(v.z); o.w = f2bf(v.w);
    *(ushort4*)(xo + d) = o;
    float xv[4] = {v.x, v.y, v.z, v.w};
#pragma unroll
    for (int q = 0; q < 4; ++q) {
      const float4* wg = (const float4*)(Wg + (size_t)(d + q) * NE);
      float4 w0 = wg[0], w1 = wg[1];
      acc[0] += (double)xv[q] * w0.x; acc[1] += (double)xv[q] * w0.y;
      acc[2] += (double)xv[q] * w0.z; acc[3] += (double)xv[q] * w0.w;
      acc[4] += (double)xv[q] * w1.x; acc[5] += (double)xv[q] * w1.y;
      acc[6] += (double)xv[q] * w1.z; acc[7] += (double)xv[q] * w1.w;
    }
  }
#pragma unroll
  for (int off = 32; off; off >>= 1)
#pragma unroll
    for (int e = 0; e < NE; ++e) acc[e] += __shfl_xor(acc[e], off);
  if (lane == 0) {
    float lg[NE];
#pragma unroll
    for (int e = 0; e < NE; ++e) lg[e] = (float)acc[e] + bg[e];
    float m = lg[0];
#pragma unroll
    for (int e = 1; e < NE; ++e) m = fmaxf(m, lg[e]);
    float s = 0.f, p[NE];
#pragma unroll
    for (int e = 0; e < NE; ++e) { p[e] = expf(lg[e] - m); s += p[e]; }
    float inv = 1.f / s;
    int i1 = 0;
#pragma unroll
    for (int e = 1; e < NE; ++e) if (lg[e] > lg[i1]) i1 = e;
    int i2 = (i1 == 0) ? 1 : 0;
#pragma unroll
    for (int e = 0; e < NE; ++e) if (e != i1 && lg[e] > lg[i2]) i2 = e;
    int pos1 = atomicAdd(&counts[i1], 1);
    btok[i1 * T_TOK + pos1] = t; bw[i1 * T_TOK + pos1] = p[i1] * inv;
    int pos2 = atomicAdd(&counts[i2], 1);
    btok[i2 * T_TOK + pos2] = t; bw[i2 * T_TOK + pos2] = p[i2] * inv;
  }
}

// in: [E][R][C] fp32 -> out: [E][C][R] bf16 (16B stores)
__global__ void k_transpose_bf16(const float* __restrict__ in, unsigned short* __restrict__ out,
                                 int R, int C) {
  __shared__ float tile[64][65];
  int e = blockIdx.z;
  int r0 = blockIdx.y * 64, c0 = blockIdx.x * 64;
  const float* src = in + (size_t)e * R * C;
  unsigned short* dst = out + (size_t)e * R * C;
  int tx = threadIdx.x & 15, ty = threadIdx.x >> 4;
#pragma unroll
  for (int i = 0; i < 4; ++i) {
    int r = ty + i * 16;
    float4 v = *(const float4*)(src + (size_t)(r0 + r) * C + c0 + tx * 4);
    tile[r][tx * 4 + 0] = v.x; tile[r][tx * 4 + 1] = v.y;
    tile[r][tx * 4 + 2] = v.z; tile[r][tx * 4 + 3] = v.w;
  }
  __syncthreads();
  int tx2 = threadIdx.x & 7, ty2 = threadIdx.x >> 3;  // 8 x 32
#pragma unroll
  for (int i = 0; i < 2; ++i) {
    int c = ty2 + i * 32;
    ushort8 o;
#pragma unroll
    for (int j = 0; j < 8; ++j) o[j] = f2bf(tile[tx2 * 8 + j][c]);
    *(ushort8*)(dst + (size_t)(c0 + c) * R + r0 + tx2 * 8) = o;
  }
}

__global__ void k_scan(const int* __restrict__ counts, int* __restrict__ offsets) {
  if (threadIdx.x == 0 && blockIdx.x == 0) {
    int s = 0;
    for (int e = 0; e < NE; ++e) { offsets[e] = s; s += counts[e]; }
  }
}

// ---------------- 128x128 tile GEMMs, BK=64, 256 threads (4 waves 2Mx2N) ----
// R8 structure (best so far): 4 blocks/CU, single-buffer LDS, 2-barrier K-step,
// hoisted stage pointers, XOR swizzle, XCD-chunked grid. NEW this round:
// nsplit=4 F-chunking so per-expert weight slices (2 MB) and the H chunk
// (32 MB) fit L2 -> stage loads L2-hit instead of L3/HBM (working-set theory).

// GEMM1: H[slot][f] = gelu(X[tok] @ W1 + b1), bf16 out.
__global__ __launch_bounds__(256, 4) void k_gemm1(
    const unsigned short* __restrict__ xb,   // [T][DM] bf16
    const unsigned short* __restrict__ w1t,  // [E][DF][DM] bf16
    const float* __restrict__ b1,            // [E][DF]
    const int* __restrict__ counts, const int* __restrict__ offsets,
    const int* __restrict__ btok,
    unsigned short* __restrict__ H,          // [2T][Fchunk] bf16
    int Fchunk, int s0, int gx, int gy) {
  __shared__ __align__(16) unsigned short ldsA[128 * 64];
  __shared__ __align__(16) unsigned short ldsB[128 * 64];
  __shared__ int toksh[128];

  int nwg = gx * gy * NE;
  int bid = blockIdx.x;
  int wg = (bid & 7) * (nwg >> 3) + (bid >> 3);
  int e = wg / (gx * gy);
  int rr = wg - e * gx * gy;
  int by = rr / gx;
  int bx = rr - by * gx;

  int cnt = counts[e];
  int m0 = by * 128;
  if (m0 >= cnt) return;
  int eoff = offsets[e];
  int f0 = bx * 128;
  int tid = threadIdx.x;
  int wave = tid >> 6, lane = tid & 63;

  for (int i = tid; i < 128; i += 256) {
    int p = m0 + i; if (p >= cnt) p = cnt - 1;
    toksh[i] = btok[e * T_TOK + p];
  }
  __syncthreads();

  int slin = lane & 7, rsub = lane >> 3;
  int ksl8 = (slin ^ rsub) * 8;  // pre-swizzled element offset within 64-wide K row

  const unsigned short* srcA[4];
  const unsigned short* srcB[4];
  int ldsg[4];
#pragma unroll
  for (int j = 0; j < 4; ++j) {
    int g = j * 4 + wave;
    int m = g * 8 + rsub;
    srcA[j] = xb + (size_t)toksh[m] * DM + ksl8;
    srcB[j] = w1t + ((size_t)e * DF + s0 + f0 + m) * DM + ksl8;
    ldsg[j] = g * 512;
  }

  auto stage = [&](int ks) {
#pragma unroll
    for (int j = 0; j < 4; ++j) {
      __builtin_amdgcn_global_load_lds((const AS1 void*)(srcA[j] + (size_t)ks * 64),
                                       (AS3 void*)(&ldsA[ldsg[j]]), 16, 0, 0);
      __builtin_amdgcn_global_load_lds((const AS1 void*)(srcB[j] + (size_t)ks * 64),
                                       (AS3 void*)(&ldsB[ldsg[j]]), 16, 0, 0);
    }
  };

  int wm = wave >> 1, wn = wave & 1;
  int lrow = lane & 15, khi = lane >> 4;
  f32x4 acc[4][4];
#pragma unroll
  for (int m = 0; m < 4; ++m)
#pragma unroll
    for (int n = 0; n < 4; ++n) acc[m][n] = (f32x4){0.f, 0.f, 0.f, 0.f};

  auto compute = [&]() {
#pragma unroll
    for (int kk = 0; kk < 2; ++kk) {
      int kslot = kk * 4 + khi;
      short8 af[4], bfv[4];
#pragma unroll
      for (int m = 0; m < 4; ++m) {
        int row = wm * 64 + m * 16 + lrow;
        int slot = kslot ^ (row & 7);
        af[m] = *(const short8*)(&ldsA[row * 64 + slot * 8]);
      }
#pragma unroll
      for (int n = 0; n < 4; ++n) {
        int row = wn * 64 + n * 16 + lrow;
        int slot = kslot ^ (row & 7);
        bfv[n] = *(const short8*)(&ldsB[row * 64 + slot * 8]);
      }
#pragma unroll
      for (int m = 0; m < 4; ++m)
#pragma unroll
        for (int n = 0; n < 4; ++n)
          acc[m][n] = __builtin_amdgcn_mfma_f32_16x16x32_bf16(af[m], bfv[n], acc[m][n], 0, 0, 0);
    }
  };

  const int nk = DM / 64;
  for (int ks = 0; ks < nk; ++ks) {
    stage(ks);
    __syncthreads();
    compute();
    __syncthreads();
  }

#pragma unroll
  for (int m = 0; m < 4; ++m) {
    int rbase = wm * 64 + m * 16 + khi * 4;
#pragma unroll
    for (int j = 0; j < 4; ++j) {
      int pos = m0 + rbase + j;
      if (pos < cnt) {
        size_t hrow = (size_t)(eoff + pos) * Fchunk;
#pragma unroll
        for (int n = 0; n < 4; ++n) {
          int fl = f0 + wn * 64 + n * 16 + lrow;
          float v = acc[m][n][j] + b1[e * DF + s0 + fl];
          H[hrow + fl] = f2bf(gelu_tanh(v));
        }
      }
    }
  }
}

// GEMM2: out[tok][d] += w * (H[slot] @ W2 + b2)
__global__ __launch_bounds__(256, 4) void k_gemm2(
    const unsigned short* __restrict__ H,    // [2T][Fchunk] bf16
    const unsigned short* __restrict__ w2t,  // [E][DM][DF] bf16
    const float* __restrict__ b2,            // [E][DM]
    const int* __restrict__ counts, const int* __restrict__ offsets,
    const int* __restrict__ btok, const float* __restrict__ bw,
    float* __restrict__ out,
    int Fchunk, int s0, int first, int gx, int gy) {
  __shared__ __align__(16) unsigned short ldsA[128 * 64];
  __shared__ __align__(16) unsigned short ldsB[128 * 64];
  __shared__ int toksh[128];
  __shared__ float wsh[128];

  int nwg = gx * gy * NE;
  int bid = blockIdx.x;
  int wg = (bid & 7) * (nwg >> 3) + (bid >> 3);
  int e = wg / (gx * gy);
  int rr = wg - e * gx * gy;
  int by = rr / gx;
  int bx = rr - by * gx;

  int cnt = counts[e];
  int m0 = by * 128;
  if (m0 >= cnt) return;
  int eoff = offsets[e];
  int d0 = bx * 128;
  int tid = threadIdx.x;
  int wave = tid >> 6, lane = tid & 63;

  for (int i = tid; i < 128; i += 256) {
    int p = m0 + i; if (p >= cnt) p = cnt - 1;
    toksh[i] = btok[e * T_TOK + p];
    wsh[i] = bw[e * T_TOK + p];
  }
  __syncthreads();

  int slin = lane & 7, rsub = lane >> 3;
  int ksl8 = (slin ^ rsub) * 8;

  const unsigned short* srcA[4];
  const unsigned short* srcB[4];
  int ldsg[4];
#pragma unroll
  for (int j = 0; j < 4; ++j) {
    int g = j * 4 + wave;
    int m = g * 8 + rsub;
    int p = m0 + m; if (p >= cnt) p = cnt - 1;
    srcA[j] = H + (size_t)(eoff + p) * Fchunk + ksl8;
    srcB[j] = w2t + ((size_t)e * DM + d0 + m) * DF + s0 + ksl8;
    ldsg[j] = g * 512;
  }

  auto stage = [&](int ks) {
#pragma unroll
    for (int j = 0; j < 4; ++j) {
      __builtin_amdgcn_global_load_lds((const AS1 void*)(srcA[j] + (size_t)ks * 64),
                                       (AS3 void*)(&ldsA[ldsg[j]]), 16, 0, 0);
      __builtin_amdgcn_global_load_lds((const AS1 void*)(srcB[j] + (size_t)ks * 64),
                                       (AS3 void*)(&ldsB[ldsg[j]]), 16, 0, 0);
    }
  };

  int wm = wave >> 1, wn = wave & 1;
  int lrow = lane & 15, khi = lane >> 4;
  f32x4 acc[4][4];
#pragma unroll
  for (int m = 0; m < 4; ++m)
#pragma unroll
    for (int n = 0; n < 4; ++n) acc[m][n] = (f32x4){0.f, 0.f, 0.f, 0.f};

  auto compute = [&]() {
#pragma unroll
    for (int kk = 0; kk < 2; ++kk) {
      int kslot = kk * 4 + khi;
      short8 af[4], bfv[4];
#pragma unroll
      for (int m = 0; m < 4; ++m) {
        int row = wm * 64 + m * 16 + lrow;
        int slot = kslot ^ (row & 7);
        af[m] = *(const short8*)(&ldsA[row * 64 + slot * 8]);
      }
#pragma unroll
      for (int n = 0; n < 4; ++n) {
        int row = wn * 64 + n * 16 + lrow;
        int slot = kslot ^ (row & 7);
        bfv[n] = *(const short8*)(&ldsB[row * 64 + slot * 8]);
      }
#pragma unroll
      for (int m = 0; m < 4; ++m)
#pragma unroll
        for (int n = 0; n < 4; ++n)
          acc[m][n] = __builtin_amdgcn_mfma_f32_16x16x32_bf16(af[m], bfv[n], acc[m][n], 0, 0, 0);
    }
  };

  const int nk = Fchunk / 64;
  for (int ks = 0; ks < nk; ++ks) {
    stage(ks);
    __syncthreads();
    compute();
    __syncthreads();
  }

#pragma unroll
  for (int m = 0; m < 4; ++m) {
    int rbase = wm * 64 + m * 16 + khi * 4;
#pragma unroll
    for (int j = 0; j < 4; ++j) {
      int lr = rbase + j;
      int pos = m0 + lr;
      if (pos < cnt) {
        int tok = toksh[lr];
        float wgt = wsh[lr];
#pragma unroll
        for (int n = 0; n < 4; ++n) {
          int dc = d0 + wn * 64 + n * 16 + lrow;
          float v = acc[m][n][j];
          if (first) v += b2[e * DM + dc];
          atomicAdd(&out[(size_t)tok * DM + dc], wgt * v);
        }
      }
    }
  }
}

extern "C" void kernel_launch(void* const* d_in, const int* in_sizes, int n_in,
                              void* d_out, int out_size, void* d_ws, size_t ws_size,
                              hipStream_t stream) {
  const float* x  = (const float*)d_in[0];
  const float* Wg = (const float*)d_in[1];
  const float* bg = (const float*)d_in[2];
  const float* W1 = (const float*)d_in[3];
  const float* b1 = (const float*)d_in[4];
  const float* W2 = (const float*)d_in[5];
  const float* b2 = (const float*)d_in[6];
  float* out = (float*)d_out;

  uint8_t* ws = (uint8_t*)d_ws;
  size_t off = 0;
  auto alloc = [&](size_t bytes) {
    size_t o = off;
    off = (off + bytes + 255) & ~(size_t)255;
    return o;
  };
  size_t o_counts = alloc(NE * 4);
  size_t o_offsets = alloc(NE * 4);
  size_t o_btok = alloc((size_t)NE * T_TOK * 4);
  size_t o_bw = alloc((size_t)NE * T_TOK * 4);
  size_t o_xb = alloc((size_t)T_TOK * DM * 2);
  size_t o_w1t = alloc((size_t)NE * DF * DM * 2);
  size_t o_w2t = alloc((size_t)NE * DM * DF * 2);
  size_t fixed = off;

  // nsplit=4 preferred: per-expert weight slices 2 MB (L2-resident per XCD),
  // H chunk 32 MB (aggregate-L2 scale). Splits partition F, so weight traffic
  // across splits is disjoint (no extra compulsory bytes).
  int nsplit = 0;
  const int splits[3] = {4, 8, 16};
  for (int si = 0; si < 3; ++si) {
    size_t need = fixed + (size_t)2 * T_TOK * (DF / splits[si]) * 2 + 256;
    if (need <= ws_size) { nsplit = splits[si]; break; }
  }
  if (!nsplit) {
    k_probe<<<dim3(1024), dim3(256), 0, stream>>>(out, (float)(double)ws_size, out_size);
    return;
  }
  int Fchunk = DF / nsplit;
  size_t o_h = alloc((size_t)2 * T_TOK * Fchunk * 2);

  int* counts = (int*)(ws + o_counts);
  int* offsets = (int*)(ws + o_offsets);
  int* btok = (int*)(ws + o_btok);
  float* bwp = (float*)(ws + o_bw);
  unsigned short* xb = (unsigned short*)(ws + o_xb);
  unsigned short* w1t = (unsigned short*)(ws + o_w1t);
  unsigned short* w2t = (unsigned short*)(ws + o_w2t);
  unsigned short* Hbuf = (unsigned short*)(ws + o_h);

  k_zero<<<dim3(2048), dim3(256), 0, stream>>>(out, T_TOK * DM, counts);
  k_prep<<<dim3(T_TOK / 4), dim3(256), 0, stream>>>(x, xb, Wg, bg, counts, btok, bwp);
  k_transpose_bf16<<<dim3(DF / 64, DM / 64, NE), dim3(256), 0, stream>>>(W1, w1t, DM, DF);
  k_transpose_bf16<<<dim3(DM / 64, DF / 64, NE), dim3(256), 0, stream>>>(W2, w2t, DF, DM);
  k_scan<<<dim3(1), dim3(64), 0, stream>>>(counts, offsets);

  int g1x = Fchunk / 128, g1y = T_TOK / 128;
  int g2x = DM / 128, g2y = T_TOK / 128;
  for (int s = 0; s < nsplit; ++s) {
    k_gemm1<<<dim3(g1x * g1y * NE), dim3(256), 0, stream>>>(
        xb, w1t, b1, counts, offsets, btok, Hbuf, Fchunk, s * Fchunk, g1x, g1y);
    k_gemm2<<<dim3(g2x * g2y * NE), dim3(256), 0, stream>>>(
        Hbuf, w2t, b2, counts, offsets, btok, bwp, out, Fchunk, s * Fchunk, s == 0, g2x, g2y);
  }
}

// Round 12
// 757.297 us; speedup vs baseline: 1.1698x; 1.1698x over previous
//
#include <hip/hip_runtime.h>
#include <hip/hip_bf16.h>
#include <stdint.h>

#define T_TOK 8192
#define DM 1024
#define DF 4096
#define NE 8

typedef __attribute__((ext_vector_type(8))) short short8;
typedef __attribute__((ext_vector_type(8))) unsigned short ushort8;
typedef __attribute__((ext_vector_type(4))) float f32x4;

#define AS1 __attribute__((address_space(1)))
#define AS3 __attribute__((address_space(3)))

static __device__ __forceinline__ unsigned short f2bf(float f) {
  union { float f; unsigned int u; } c; c.f = f;
  unsigned int u = c.u;
  unsigned int r = (u + 0x7FFFu + ((u >> 16) & 1u)) >> 16;
  return (unsigned short)r;
}

static __device__ __forceinline__ float gelu_tanh(float v) {
  float y = 0.7978845608028654f * (v + 0.044715f * v * v * v);
  float ay = fabsf(y);
  float e = __expf(-2.0f * ay);
  float th = (1.0f - e) / (1.0f + e);
  th = copysignf(th, y);
  return 0.5f * v * (1.0f + th);
}

__global__ void k_probe(float* out, float v, int n) {
  int i = blockIdx.x * blockDim.x + threadIdx.x;
  for (; i < n; i += gridDim.x * blockDim.x) out[i] = v;
}

// Gating (fp64-exact) + x->bf16 + out-zeroing. NO atomics: writes per-token
// {expert, weight} pairs; compaction happens in k_bucket.
__global__ void k_gate(const float* __restrict__ x, unsigned short* __restrict__ xb,
                       const float* __restrict__ Wg, const float* __restrict__ bg,
                       int* __restrict__ choice2, float* __restrict__ wts,
                       float* __restrict__ out) {
  {  // zero out[] (stream-ordered well before gemm2)
    int gid = blockIdx.x * blockDim.x + threadIdx.x;
    float4 z = {0.f, 0.f, 0.f, 0.f};
    float4* o4 = (float4*)out;
#pragma unroll
    for (int i = 0; i < 4; ++i) o4[gid + i * 524288] = z;
  }
  int wave = threadIdx.x >> 6, lane = threadIdx.x & 63;
  int t = blockIdx.x * 4 + wave;
  const float* xr = x + (size_t)t * DM;
  unsigned short* xo = xb + (size_t)t * DM;
  double acc[NE];
#pragma unroll
  for (int e = 0; e < NE; ++e) acc[e] = 0.0;
#pragma unroll
  for (int i = 0; i < 4; ++i) {
    int d = lane * 4 + i * 256;
    float4 v = *(const float4*)(xr + d);
    ushort4 o;
    o.x = f2bf(v.x); o.y = f2bf(v.y); o.z = f2bf(v.z); o.w = f2bf(v.w);
    *(ushort4*)(xo + d) = o;
    float xv[4] = {v.x, v.y, v.z, v.w};
#pragma unroll
    for (int q = 0; q < 4; ++q) {
      const float4* wg = (const float4*)(Wg + (size_t)(d + q) * NE);
      float4 w0 = wg[0], w1 = wg[1];
      acc[0] += (double)xv[q] * w0.x; acc[1] += (double)xv[q] * w0.y;
      acc[2] += (double)xv[q] * w0.z; acc[3] += (double)xv[q] * w0.w;
      acc[4] += (double)xv[q] * w1.x; acc[5] += (double)xv[q] * w1.y;
      acc[6] += (double)xv[q] * w1.z; acc[7] += (double)xv[q] * w1.w;
    }
  }
#pragma unroll
  for (int off = 32; off; off >>= 1)
#pragma unroll
    for (int e = 0; e < NE; ++e) acc[e] += __shfl_xor(acc[e], off);
  if (lane == 0) {
    float lg[NE];
#pragma unroll
    for (int e = 0; e < NE; ++e) lg[e] = (float)acc[e] + bg[e];
    float m = lg[0];
#pragma unroll
    for (int e = 1; e < NE; ++e) m = fmaxf(m, lg[e]);
    float s = 0.f, p[NE];
#pragma unroll
    for (int e = 0; e < NE; ++e) { p[e] = expf(lg[e] - m); s += p[e]; }
    float inv = 1.f / s;
    int i1 = 0;
#pragma unroll
    for (int e = 1; e < NE; ++e) if (lg[e] > lg[i1]) i1 = e;
    int i2 = (i1 == 0) ? 1 : 0;
#pragma unroll
    for (int e = 0; e < NE; ++e) if (e != i1 && lg[e] > lg[i2]) i2 = e;
    choice2[2 * t] = i1;     wts[2 * t] = p[i1] * inv;
    choice2[2 * t + 1] = i2; wts[2 * t + 1] = p[i2] * inv;
  }
}

// Deterministic wave-per-expert compaction. 512 thr = 8 waves; wave w owns
// expert w. No atomics, no dynamic register indexing, wave-uniform control
// flow. Each wave scans all 16384 items (64/chunk), ballot+rank placement.
__global__ void k_bucket(const int* __restrict__ choice2, const float* __restrict__ wts,
                         int* __restrict__ counts, int* __restrict__ offsets,
                         int* __restrict__ btok, float* __restrict__ bw) {
  int tid = threadIdx.x;
  int w = tid >> 6, lane = tid & 63;
  unsigned long long below = (lane == 0) ? 0ull : ((1ull << lane) - 1ull);
  int cnt = 0;  // wave-uniform running count for expert w
  for (int i0 = 0; i0 < 2 * T_TOK; i0 += 64) {
    int idx = i0 + lane;
    int e = choice2[idx];
    float wt = wts[idx];
    unsigned long long m = __ballot(e == w);
    if (e == w) {
      int r = (int)__popcll(m & below);
      btok[w * T_TOK + cnt + r] = idx >> 1;
      bw[w * T_TOK + cnt + r] = wt;
    }
    cnt += (int)__popcll(m);
  }
  if (lane == 0) counts[w] = cnt;
  __syncthreads();
  if (tid == 0) {
    int s = 0;
    for (int e = 0; e < NE; ++e) { offsets[e] = s; s += counts[e]; }
  }
}

// in: [E][R][C] fp32 -> out: [E][C][R] bf16 (16B stores)
__global__ void k_transpose_bf16(const float* __restrict__ in, unsigned short* __restrict__ out,
                                 int R, int C) {
  __shared__ float tile[64][65];
  int e = blockIdx.z;
  int r0 = blockIdx.y * 64, c0 = blockIdx.x * 64;
  const float* src = in + (size_t)e * R * C;
  unsigned short* dst = out + (size_t)e * R * C;
  int tx = threadIdx.x & 15, ty = threadIdx.x >> 4;
#pragma unroll
  for (int i = 0; i < 4; ++i) {
    int r = ty + i * 16;
    float4 v = *(const float4*)(src + (size_t)(r0 + r) * C + c0 + tx * 4);
    tile[r][tx * 4 + 0] = v.x; tile[r][tx * 4 + 1] = v.y;
    tile[r][tx * 4 + 2] = v.z; tile[r][tx * 4 + 3] = v.w;
  }
  __syncthreads();
  int tx2 = threadIdx.x & 7, ty2 = threadIdx.x >> 3;  // 8 x 32
#pragma unroll
  for (int i = 0; i < 2; ++i) {
    int c = ty2 + i * 32;
    ushort8 o;
#pragma unroll
    for (int j = 0; j < 8; ++j) o[j] = f2bf(tile[tx2 * 8 + j][c]);
    *(ushort8*)(dst + (size_t)(c0 + c) * R + r0 + tx2 * 8) = o;
  }
}

// ---------------- 128x128 tile GEMMs, BK=64, 256 threads (4 waves 2Mx2N) ----
// R8 structure (best): 4 blocks/CU, single-buffer LDS, 2-barrier K-step,
// hoisted stage pointers, XOR swizzle, XCD-chunked grid, nsplit=1.

// GEMM1: H[slot][f] = gelu(X[tok] @ W1 + b1), bf16 out.
__global__ __launch_bounds__(256, 4) void k_gemm1(
    const unsigned short* __restrict__ xb,   // [T][DM] bf16
    const unsigned short* __restrict__ w1t,  // [E][DF][DM] bf16
    const float* __restrict__ b1,            // [E][DF]
    const int* __restrict__ counts, const int* __restrict__ offsets,
    const int* __restrict__ btok,
    unsigned short* __restrict__ H,          // [2T][Fchunk] bf16
    int Fchunk, int s0, int gx, int gy) {
  __shared__ __align__(16) unsigned short ldsA[128 * 64];
  __shared__ __align__(16) unsigned short ldsB[128 * 64];
  __shared__ int toksh[128];

  int nwg = gx * gy * NE;
  int bid = blockIdx.x;
  int wg = (bid & 7) * (nwg >> 3) + (bid >> 3);
  int e = wg / (gx * gy);
  int rr = wg - e * gx * gy;
  int by = rr / gx;
  int bx = rr - by * gx;

  int cnt = counts[e];
  int m0 = by * 128;
  if (m0 >= cnt) return;
  int eoff = offsets[e];
  int f0 = bx * 128;
  int tid = threadIdx.x;
  int wave = tid >> 6, lane = tid & 63;

  for (int i = tid; i < 128; i += 256) {
    int p = m0 + i; if (p >= cnt) p = cnt - 1;
    toksh[i] = btok[e * T_TOK + p];
  }
  __syncthreads();

  int slin = lane & 7, rsub = lane >> 3;
  int ksl8 = (slin ^ rsub) * 8;

  const unsigned short* srcA[4];
  const unsigned short* srcB[4];
  int ldsg[4];
#pragma unroll
  for (int j = 0; j < 4; ++j) {
    int g = j * 4 + wave;
    int m = g * 8 + rsub;
    srcA[j] = xb + (size_t)toksh[m] * DM + ksl8;
    srcB[j] = w1t + ((size_t)e * DF + s0 + f0 + m) * DM + ksl8;
    ldsg[j] = g * 512;
  }

  auto stage = [&](int ks) {
#pragma unroll
    for (int j = 0; j < 4; ++j) {
      __builtin_amdgcn_global_load_lds((const AS1 void*)(srcA[j] + (size_t)ks * 64),
                                       (AS3 void*)(&ldsA[ldsg[j]]), 16, 0, 0);
      __builtin_amdgcn_global_load_lds((const AS1 void*)(srcB[j] + (size_t)ks * 64),
                                       (AS3 void*)(&ldsB[ldsg[j]]), 16, 0, 0);
    }
  };

  int wm = wave >> 1, wn = wave & 1;
  int lrow = lane & 15, khi = lane >> 4;
  f32x4 acc[4][4];
#pragma unroll
  for (int m = 0; m < 4; ++m)
#pragma unroll
    for (int n = 0; n < 4; ++n) acc[m][n] = (f32x4){0.f, 0.f, 0.f, 0.f};

  auto compute = [&]() {
#pragma unroll
    for (int kk = 0; kk < 2; ++kk) {
      int kslot = kk * 4 + khi;
      short8 af[4], bfv[4];
#pragma unroll
      for (int m = 0; m < 4; ++m) {
        int row = wm * 64 + m * 16 + lrow;
        int slot = kslot ^ (row & 7);
        af[m] = *(const short8*)(&ldsA[row * 64 + slot * 8]);
      }
#pragma unroll
      for (int n = 0; n < 4; ++n) {
        int row = wn * 64 + n * 16 + lrow;
        int slot = kslot ^ (row & 7);
        bfv[n] = *(const short8*)(&ldsB[row * 64 + slot * 8]);
      }
#pragma unroll
      for (int m = 0; m < 4; ++m)
#pragma unroll
        for (int n = 0; n < 4; ++n)
          acc[m][n] = __builtin_amdgcn_mfma_f32_16x16x32_bf16(af[m], bfv[n], acc[m][n], 0, 0, 0);
    }
  };

  const int nk = DM / 64;
  for (int ks = 0; ks < nk; ++ks) {
    stage(ks);
    __syncthreads();
    compute();
    __syncthreads();
  }

#pragma unroll
  for (int m = 0; m < 4; ++m) {
    int rbase = wm * 64 + m * 16 + khi * 4;
#pragma unroll
    for (int j = 0; j < 4; ++j) {
      int pos = m0 + rbase + j;
      if (pos < cnt) {
        size_t hrow = (size_t)(eoff + pos) * Fchunk;
#pragma unroll
        for (int n = 0; n < 4; ++n) {
          int fl = f0 + wn * 64 + n * 16 + lrow;
          float v = acc[m][n][j] + b1[e * DF + s0 + fl];
          H[hrow + fl] = f2bf(gelu_tanh(v));
        }
      }
    }
  }
}

// GEMM2: out[tok][d] += w * (H[slot] @ W2 + b2)
__global__ __launch_bounds__(256, 4) void k_gemm2(
    const unsigned short* __restrict__ H,    // [2T][Fchunk] bf16
    const unsigned short* __restrict__ w2t,  // [E][DM][DF] bf16
    const float* __restrict__ b2,            // [E][DM]
    const int* __restrict__ counts, const int* __restrict__ offsets,
    const int* __restrict__ btok, const float* __restrict__ bw,
    float* __restrict__ out,
    int Fchunk, int s0, int first, int gx, int gy) {
  __shared__ __align__(16) unsigned short ldsA[128 * 64];
  __shared__ __align__(16) unsigned short ldsB[128 * 64];
  __shared__ int toksh[128];
  __shared__ float wsh[128];

  int nwg = gx * gy * NE;
  int bid = blockIdx.x;
  int wg = (bid & 7) * (nwg >> 3) + (bid >> 3);
  int e = wg / (gx * gy);
  int rr = wg - e * gx * gy;
  int by = rr / gx;
  int bx = rr - by * gx;

  int cnt = counts[e];
  int m0 = by * 128;
  if (m0 >= cnt) return;
  int eoff = offsets[e];
  int d0 = bx * 128;
  int tid = threadIdx.x;
  int wave = tid >> 6, lane = tid & 63;

  for (int i = tid; i < 128; i += 256) {
    int p = m0 + i; if (p >= cnt) p = cnt - 1;
    toksh[i] = btok[e * T_TOK + p];
    wsh[i] = bw[e * T_TOK + p];
  }
  __syncthreads();

  int slin = lane & 7, rsub = lane >> 3;
  int ksl8 = (slin ^ rsub) * 8;

  const unsigned short* srcA[4];
  const unsigned short* srcB[4];
  int ldsg[4];
#pragma unroll
  for (int j = 0; j < 4; ++j) {
    int g = j * 4 + wave;
    int m = g * 8 + rsub;
    int p = m0 + m; if (p >= cnt) p = cnt - 1;
    srcA[j] = H + (size_t)(eoff + p) * Fchunk + ksl8;
    srcB[j] = w2t + ((size_t)e * DM + d0 + m) * DF + s0 + ksl8;
    ldsg[j] = g * 512;
  }

  auto stage = [&](int ks) {
#pragma unroll
    for (int j = 0; j < 4; ++j) {
      __builtin_amdgcn_global_load_lds((const AS1 void*)(srcA[j] + (size_t)ks * 64),
                                       (AS3 void*)(&ldsA[ldsg[j]]), 16, 0, 0);
      __builtin_amdgcn_global_load_lds((const AS1 void*)(srcB[j] + (size_t)ks * 64),
                                       (AS3 void*)(&ldsB[ldsg[j]]), 16, 0, 0);
    }
  };

  int wm = wave >> 1, wn = wave & 1;
  int lrow = lane & 15, khi = lane >> 4;
  f32x4 acc[4][4];
#pragma unroll
  for (int m = 0; m < 4; ++m)
#pragma unroll
    for (int n = 0; n < 4; ++n) acc[m][n] = (f32x4){0.f, 0.f, 0.f, 0.f};

  auto compute = [&]() {
#pragma unroll
    for (int kk = 0; kk < 2; ++kk) {
      int kslot = kk * 4 + khi;
      short8 af[4], bfv[4];
#pragma unroll
      for (int m = 0; m < 4; ++m) {
        int row = wm * 64 + m * 16 + lrow;
        int slot = kslot ^ (row & 7);
        af[m] = *(const short8*)(&ldsA[row * 64 + slot * 8]);
      }
#pragma unroll
      for (int n = 0; n < 4; ++n) {
        int row = wn * 64 + n * 16 + lrow;
        int slot = kslot ^ (row & 7);
        bfv[n] = *(const short8*)(&ldsB[row * 64 + slot * 8]);
      }
#pragma unroll
      for (int m = 0; m < 4; ++m)
#pragma unroll
        for (int n = 0; n < 4; ++n)
          acc[m][n] = __builtin_amdgcn_mfma_f32_16x16x32_bf16(af[m], bfv[n], acc[m][n], 0, 0, 0);
    }
  };

  const int nk = Fchunk / 64;
  for (int ks = 0; ks < nk; ++ks) {
    stage(ks);
    __syncthreads();
    compute();
    __syncthreads();
  }

#pragma unroll
  for (int m = 0; m < 4; ++m) {
    int rbase = wm * 64 + m * 16 + khi * 4;
#pragma unroll
    for (int j = 0; j < 4; ++j) {
      int lr = rbase + j;
      int pos = m0 + lr;
      if (pos < cnt) {
        int tok = toksh[lr];
        float wgt = wsh[lr];
#pragma unroll
        for (int n = 0; n < 4; ++n) {
          int dc = d0 + wn * 64 + n * 16 + lrow;
          float v = acc[m][n][j];
          if (first) v += b2[e * DM + dc];
          atomicAdd(&out[(size_t)tok * DM + dc], wgt * v);
        }
      }
    }
  }
}

extern "C" void kernel_launch(void* const* d_in, const int* in_sizes, int n_in,
                              void* d_out, int out_size, void* d_ws, size_t ws_size,
                              hipStream_t stream) {
  const float* x  = (const float*)d_in[0];
  const float* Wg = (const float*)d_in[1];
  const float* bg = (const float*)d_in[2];
  const float* W1 = (const float*)d_in[3];
  const float* b1 = (const float*)d_in[4];
  const float* W2 = (const float*)d_in[5];
  const float* b2 = (const float*)d_in[6];
  float* out = (float*)d_out;

  uint8_t* ws = (uint8_t*)d_ws;
  size_t off = 0;
  auto alloc = [&](size_t bytes) {
    size_t o = off;
    off = (off + bytes + 255) & ~(size_t)255;
    return o;
  };
  size_t o_counts = alloc(NE * 4);
  size_t o_offsets = alloc(NE * 4);
  size_t o_choice = alloc((size_t)2 * T_TOK * 4);
  size_t o_wts = alloc((size_t)2 * T_TOK * 4);
  size_t o_btok = alloc((size_t)NE * T_TOK * 4);
  size_t o_bw = alloc((size_t)NE * T_TOK * 4);
  size_t o_xb = alloc((size_t)T_TOK * DM * 2);
  size_t o_w1t = alloc((size_t)NE * DF * DM * 2);
  size_t o_w2t = alloc((size_t)NE * DM * DF * 2);
  size_t fixed = off;

  int nsplit = 0;
  const int splits[5] = {1, 2, 4, 8, 16};
  for (int si = 0; si < 5; ++si) {
    size_t need = fixed + (size_t)2 * T_TOK * (DF / splits[si]) * 2 + 256;
    if (need <= ws_size) { nsplit = splits[si]; break; }
  }
  if (!nsplit) {
    k_probe<<<dim3(1024), dim3(256), 0, stream>>>(out, (float)(double)ws_size, out_size);
    return;
  }
  int Fchunk = DF / nsplit;
  size_t o_h = alloc((size_t)2 * T_TOK * Fchunk * 2);

  int* counts = (int*)(ws + o_counts);
  int* offsets = (int*)(ws + o_offsets);
  int* choice2 = (int*)(ws + o_choice);
  float* wtsp = (float*)(ws + o_wts);
  int* btok = (int*)(ws + o_btok);
  float* bwp = (float*)(ws + o_bw);
  unsigned short* xb = (unsigned short*)(ws + o_xb);
  unsigned short* w1t = (unsigned short*)(ws + o_w1t);
  unsigned short* w2t = (unsigned short*)(ws + o_w2t);
  unsigned short* Hbuf = (unsigned short*)(ws + o_h);

  k_gate<<<dim3(T_TOK / 4), dim3(256), 0, stream>>>(x, xb, Wg, bg, choice2, wtsp, out);
  k_transpose_bf16<<<dim3(DF / 64, DM / 64, NE), dim3(256), 0, stream>>>(W1, w1t, DM, DF);
  k_transpose_bf16<<<dim3(DM / 64, DF / 64, NE), dim3(256), 0, stream>>>(W2, w2t, DF, DM);
  k_bucket<<<dim3(1), dim3(512), 0, stream>>>(choice2, wtsp, counts, offsets, btok, bwp);

  int g1x = Fchunk / 128, g1y = T_TOK / 128;
  int g2x = DM / 128, g2y = T_TOK / 128;
  for (int s = 0; s < nsplit; ++s) {
    k_gemm1<<<dim3(g1x * g1y * NE), dim3(256), 0, stream>>>(
        xb, w1t, b1, counts, offsets, btok, Hbuf, Fchunk, s * Fchunk, g1x, g1y);
    k_gemm2<<<dim3(g2x * g2y * NE), dim3(256), 0, stream>>>(
        Hbuf, w2t, b2, counts, offsets, btok, bwp, out, Fchunk, s * Fchunk, s == 0, g2x, g2y);
  }
}

// Round 13
// 591.937 us; speedup vs baseline: 1.4966x; 1.2794x over previous
//
#include <hip/hip_runtime.h>
#include <hip/hip_bf16.h>
#include <stdint.h>

#define T_TOK 8192
#define DM 1024
#define DF 4096
#define NE 8
#define NSLOT 136   // max live by-slots: 16384/128 + 8

typedef __attribute__((ext_vector_type(8))) short short8;
typedef __attribute__((ext_vector_type(8))) unsigned short ushort8;
typedef __attribute__((ext_vector_type(4))) float f32x4;

#define AS1 __attribute__((address_space(1)))
#define AS3 __attribute__((address_space(3)))

static __device__ __forceinline__ unsigned short f2bf(float f) {
  union { float f; unsigned int u; } c; c.f = f;
  unsigned int u = c.u;
  unsigned int r = (u + 0x7FFFu + ((u >> 16) & 1u)) >> 16;
  return (unsigned short)r;
}

static __device__ __forceinline__ float gelu_tanh(float v) {
  float y = 0.7978845608028654f * (v + 0.044715f * v * v * v);
  float ay = fabsf(y);
  float e = __expf(-2.0f * ay);
  float th = (1.0f - e) / (1.0f + e);
  th = copysignf(th, y);
  return 0.5f * v * (1.0f + th);
}

__global__ void k_probe(float* out, float v, int n) {
  int i = blockIdx.x * blockDim.x + threadIdx.x;
  for (; i < n; i += gridDim.x * blockDim.x) out[i] = v;
}

// Gating (fp64-exact) + x->bf16. No atomics; writes per-token {expert, weight}.
__global__ void k_gate(const float* __restrict__ x, unsigned short* __restrict__ xb,
                       const float* __restrict__ Wg, const float* __restrict__ bg,
                       int* __restrict__ choice2, float* __restrict__ wts) {
  int wave = threadIdx.x >> 6, lane = threadIdx.x & 63;
  int t = blockIdx.x * 4 + wave;
  const float* xr = x + (size_t)t * DM;
  unsigned short* xo = xb + (size_t)t * DM;
  double acc[NE];
#pragma unroll
  for (int e = 0; e < NE; ++e) acc[e] = 0.0;
#pragma unroll
  for (int i = 0; i < 4; ++i) {
    int d = lane * 4 + i * 256;
    float4 v = *(const float4*)(xr + d);
    ushort4 o;
    o.x = f2bf(v.x); o.y = f2bf(v.y); o.z = f2bf(v.z); o.w = f2bf(v.w);
    *(ushort4*)(xo + d) = o;
    float xv[4] = {v.x, v.y, v.z, v.w};
#pragma unroll
    for (int q = 0; q < 4; ++q) {
      const float4* wg = (const float4*)(Wg + (size_t)(d + q) * NE);
      float4 w0 = wg[0], w1 = wg[1];
      acc[0] += (double)xv[q] * w0.x; acc[1] += (double)xv[q] * w0.y;
      acc[2] += (double)xv[q] * w0.z; acc[3] += (double)xv[q] * w0.w;
      acc[4] += (double)xv[q] * w1.x; acc[5] += (double)xv[q] * w1.y;
      acc[6] += (double)xv[q] * w1.z; acc[7] += (double)xv[q] * w1.w;
    }
  }
#pragma unroll
  for (int off = 32; off; off >>= 1)
#pragma unroll
    for (int e = 0; e < NE; ++e) acc[e] += __shfl_xor(acc[e], off);
  if (lane == 0) {
    float lg[NE];
#pragma unroll
    for (int e = 0; e < NE; ++e) lg[e] = (float)acc[e] + bg[e];
    float m = lg[0];
#pragma unroll
    for (int e = 1; e < NE; ++e) m = fmaxf(m, lg[e]);
    float s = 0.f, p[NE];
#pragma unroll
    for (int e = 0; e < NE; ++e) { p[e] = expf(lg[e] - m); s += p[e]; }
    float inv = 1.f / s;
    int i1 = 0;
#pragma unroll
    for (int e = 1; e < NE; ++e) if (lg[e] > lg[i1]) i1 = e;
    int i2 = (i1 == 0) ? 1 : 0;
#pragma unroll
    for (int e = 0; e < NE; ++e) if (e != i1 && lg[e] > lg[i2]) i2 = e;
    choice2[2 * t] = i1;     wts[2 * t] = p[i1] * inv;
    choice2[2 * t + 1] = i2; wts[2 * t + 1] = p[i2] * inv;
  }
}

// Two-phase deterministic compaction + work-queue build. 1024 thr = 16 waves:
// wave w: expert w&7, half w>>3. No global atomics, wave-uniform flow.
__global__ void k_bucket(const int* __restrict__ choice2, const float* __restrict__ wts,
                         int* __restrict__ counts, int* __restrict__ offsets,
                         int* __restrict__ btok, float* __restrict__ bw,
                         int* __restrict__ work) {
  __shared__ int c2[16];
  int tid = threadIdx.x;
  int w = tid >> 6, lane = tid & 63;
  int e = w & 7, h = w >> 3;
  int base0 = h * T_TOK;  // half-range start (8192 items per half)
  unsigned long long below = (lane == 0) ? 0ull : ((1ull << lane) - 1ull);
  // phase 1: count my half
  int cnt = 0;
  for (int i0 = 0; i0 < T_TOK; i0 += 64) {
    int ce = choice2[base0 + i0 + lane];
    cnt += (int)__popcll(__ballot(ce == e));
  }
  if (lane == 0) c2[w] = cnt;
  __syncthreads();
  if (tid == 0) {
    int s = 0;
    for (int q = 0; q < NE; ++q) {
      counts[q] = c2[q] + c2[q + 8];
      offsets[q] = s; s += counts[q];
    }
    int idx = 0;
    for (int q = 0; q < NE; ++q) {
      int nby = (counts[q] + 127) >> 7;
      for (int j = 0; j < nby; ++j) work[idx++] = (q << 20) | (j << 7);
    }
    while (idx < NSLOT) work[idx++] = -1;
  }
  __syncthreads();
  // phase 2: place my half at [h ? firstHalfCount : 0]
  int pos = h ? c2[e] : 0;
  for (int i0 = 0; i0 < T_TOK; i0 += 64) {
    int idx = base0 + i0 + lane;
    int ce = choice2[idx];
    float wt = wts[idx];
    unsigned long long m = __ballot(ce == e);
    if (ce == e) {
      int r = (int)__popcll(m & below);
      btok[e * T_TOK + pos + r] = idx >> 1;
      bw[e * T_TOK + pos + r] = wt;
    }
    pos += (int)__popcll(m);
  }
}

// out[t][d] = w0*b2[e0][d] + w1*b2[e1][d]  (bias pre-applied; gemm2 adds on top)
__global__ void k_outinit(const int* __restrict__ choice2, const float* __restrict__ wts,
                          const float* __restrict__ b2, float* __restrict__ out) {
  int t = blockIdx.x;
  int e0 = choice2[2 * t], e1 = choice2[2 * t + 1];
  float w0 = wts[2 * t], w1 = wts[2 * t + 1];
  int d = threadIdx.x * 4;
  float4 a = *(const float4*)(b2 + (size_t)e0 * DM + d);
  float4 b = *(const float4*)(b2 + (size_t)e1 * DM + d);
  float4 o;
  o.x = w0 * a.x + w1 * b.x; o.y = w0 * a.y + w1 * b.y;
  o.z = w0 * a.z + w1 * b.z; o.w = w0 * a.w + w1 * b.w;
  *(float4*)(out + (size_t)t * DM + d) = o;
}

// in: [E][R][C] fp32 -> out: [E][C][R] bf16 (16B stores)
__global__ void k_transpose_bf16(const float* __restrict__ in, unsigned short* __restrict__ out,
                                 int R, int C) {
  __shared__ float tile[64][65];
  int e = blockIdx.z;
  int r0 = blockIdx.y * 64, c0 = blockIdx.x * 64;
  const float* src = in + (size_t)e * R * C;
  unsigned short* dst = out + (size_t)e * R * C;
  int tx = threadIdx.x & 15, ty = threadIdx.x >> 4;
#pragma unroll
  for (int i = 0; i < 4; ++i) {
    int r = ty + i * 16;
    float4 v = *(const float4*)(src + (size_t)(r0 + r) * C + c0 + tx * 4);
    tile[r][tx * 4 + 0] = v.x; tile[r][tx * 4 + 1] = v.y;
    tile[r][tx * 4 + 2] = v.z; tile[r][tx * 4 + 3] = v.w;
  }
  __syncthreads();
  int tx2 = threadIdx.x & 7, ty2 = threadIdx.x >> 3;  // 8 x 32
#pragma unroll
  for (int i = 0; i < 2; ++i) {
    int c = ty2 + i * 32;
    ushort8 o;
#pragma unroll
    for (int j = 0; j < 8; ++j) o[j] = f2bf(tile[tx2 * 8 + j][c]);
    *(ushort8*)(dst + (size_t)(c0 + c) * R + r0 + tx2 * 8) = o;
  }
}

// ---------------- 128x128 tile GEMMs, BK=64, 256 threads (4 waves 2Mx2N) ----
// R8 GEMM core untouched. NEW: compact work-queue grid (no dead blocks) so the
// XCD-chunked swizzle maps LIVE blocks; consecutive wg share the A-panel.

// GEMM1: H[slot][f] = gelu(X[tok] @ W1 + b1), bf16 out.
__global__ __launch_bounds__(256, 4) void k_gemm1(
    const unsigned short* __restrict__ xb,   // [T][DM] bf16
    const unsigned short* __restrict__ w1t,  // [E][DF][DM] bf16
    const float* __restrict__ b1,            // [E][DF]
    const int* __restrict__ counts, const int* __restrict__ offsets,
    const int* __restrict__ btok, const int* __restrict__ work,
    unsigned short* __restrict__ H,          // [2T][DF] bf16
    int gx) {
  __shared__ __align__(16) unsigned short ldsA[128 * 64];
  __shared__ __align__(16) unsigned short ldsB[128 * 64];
  __shared__ int toksh[128];

  int nwg = gx * NSLOT;
  int bid = blockIdx.x;
  int wg = (bid & 7) * (nwg >> 3) + (bid >> 3);
  int slot = wg / gx;
  int bx = wg - slot * gx;
  int pk = work[slot];
  if (pk < 0) return;
  int e = pk >> 20;
  int m0 = pk & 0xFFFFF;
  int cnt = counts[e];
  int eoff = offsets[e];
  int f0 = bx * 128;
  int tid = threadIdx.x;
  int wave = tid >> 6, lane = tid & 63;

  for (int i = tid; i < 128; i += 256) {
    int p = m0 + i; if (p >= cnt) p = cnt - 1;
    toksh[i] = btok[e * T_TOK + p];
  }
  __syncthreads();

  int slin = lane & 7, rsub = lane >> 3;
  int ksl8 = (slin ^ rsub) * 8;

  const unsigned short* srcA[4];
  const unsigned short* srcB[4];
  int ldsg[4];
#pragma unroll
  for (int j = 0; j < 4; ++j) {
    int g = j * 4 + wave;
    int m = g * 8 + rsub;
    srcA[j] = xb + (size_t)toksh[m] * DM + ksl8;
    srcB[j] = w1t + ((size_t)e * DF + f0 + m) * DM + ksl8;
    ldsg[j] = g * 512;
  }

  auto stage = [&](int ks) {
#pragma unroll
    for (int j = 0; j < 4; ++j) {
      __builtin_amdgcn_global_load_lds((const AS1 void*)(srcA[j] + (size_t)ks * 64),
                                       (AS3 void*)(&ldsA[ldsg[j]]), 16, 0, 0);
      __builtin_amdgcn_global_load_lds((const AS1 void*)(srcB[j] + (size_t)ks * 64),
                                       (AS3 void*)(&ldsB[ldsg[j]]), 16, 0, 0);
    }
  };

  int wm = wave >> 1, wn = wave & 1;
  int lrow = lane & 15, khi = lane >> 4;
  f32x4 acc[4][4];
#pragma unroll
  for (int m = 0; m < 4; ++m)
#pragma unroll
    for (int n = 0; n < 4; ++n) acc[m][n] = (f32x4){0.f, 0.f, 0.f, 0.f};

  auto compute = [&]() {
#pragma unroll
    for (int kk = 0; kk < 2; ++kk) {
      int kslot = kk * 4 + khi;
      short8 af[4], bfv[4];
#pragma unroll
      for (int m = 0; m < 4; ++m) {
        int row = wm * 64 + m * 16 + lrow;
        int slotx = kslot ^ (row & 7);
        af[m] = *(const short8*)(&ldsA[row * 64 + slotx * 8]);
      }
#pragma unroll
      for (int n = 0; n < 4; ++n) {
        int row = wn * 64 + n * 16 + lrow;
        int slotx = kslot ^ (row & 7);
        bfv[n] = *(const short8*)(&ldsB[row * 64 + slotx * 8]);
      }
#pragma unroll
      for (int m = 0; m < 4; ++m)
#pragma unroll
        for (int n = 0; n < 4; ++n)
          acc[m][n] = __builtin_amdgcn_mfma_f32_16x16x32_bf16(af[m], bfv[n], acc[m][n], 0, 0, 0);
    }
  };

  const int nk = DM / 64;
  for (int ks = 0; ks < nk; ++ks) {
    stage(ks);
    __syncthreads();
    compute();
    __syncthreads();
  }

#pragma unroll
  for (int m = 0; m < 4; ++m) {
    int rbase = wm * 64 + m * 16 + khi * 4;
#pragma unroll
    for (int j = 0; j < 4; ++j) {
      int pos = m0 + rbase + j;
      if (pos < cnt) {
        size_t hrow = (size_t)(eoff + pos) * DF;
#pragma unroll
        for (int n = 0; n < 4; ++n) {
          int fl = f0 + wn * 64 + n * 16 + lrow;
          float v = acc[m][n][j] + b1[e * DF + fl];
          H[hrow + fl] = f2bf(gelu_tanh(v));
        }
      }
    }
  }
}

// GEMM2: out[tok][d] += w * (H[slot] @ W2)   (bias pre-applied by k_outinit)
__global__ __launch_bounds__(256, 4) void k_gemm2(
    const unsigned short* __restrict__ H,    // [2T][DF] bf16
    const unsigned short* __restrict__ w2t,  // [E][DM][DF] bf16
    const int* __restrict__ counts, const int* __restrict__ offsets,
    const int* __restrict__ btok, const float* __restrict__ bw,
    const int* __restrict__ work,
    float* __restrict__ out, int gx) {
  __shared__ __align__(16) unsigned short ldsA[128 * 64];
  __shared__ __align__(16) unsigned short ldsB[128 * 64];
  __shared__ int toksh[128];
  __shared__ float wsh[128];

  int nwg = gx * NSLOT;
  int bid = blockIdx.x;
  int wg = (bid & 7) * (nwg >> 3) + (bid >> 3);
  int slot = wg / gx;
  int bx = wg - slot * gx;
  int pk = work[slot];
  if (pk < 0) return;
  int e = pk >> 20;
  int m0 = pk & 0xFFFFF;
  int cnt = counts[e];
  int eoff = offsets[e];
  int d0 = bx * 128;
  int tid = threadIdx.x;
  int wave = tid >> 6, lane = tid & 63;

  for (int i = tid; i < 128; i += 256) {
    int p = m0 + i; if (p >= cnt) p = cnt - 1;
    toksh[i] = btok[e * T_TOK + p];
    wsh[i] = bw[e * T_TOK + p];
  }
  __syncthreads();

  int slin = lane & 7, rsub = lane >> 3;
  int ksl8 = (slin ^ rsub) * 8;

  const unsigned short* srcA[4];
  const unsigned short* srcB[4];
  int ldsg[4];
#pragma unroll
  for (int j = 0; j < 4; ++j) {
    int g = j * 4 + wave;
    int m = g * 8 + rsub;
    int p = m0 + m; if (p >= cnt) p = cnt - 1;
    srcA[j] = H + (size_t)(eoff + p) * DF + ksl8;
    srcB[j] = w2t + ((size_t)e * DM + d0 + m) * DF + ksl8;
    ldsg[j] = g * 512;
  }

  auto stage = [&](int ks) {
#pragma unroll
    for (int j = 0; j < 4; ++j) {
      __builtin_amdgcn_global_load_lds((const AS1 void*)(srcA[j] + (size_t)ks * 64),
                                       (AS3 void*)(&ldsA[ldsg[j]]), 16, 0, 0);
      __builtin_amdgcn_global_load_lds((const AS1 void*)(srcB[j] + (size_t)ks * 64),
                                       (AS3 void*)(&ldsB[ldsg[j]]), 16, 0, 0);
    }
  };

  int wm = wave >> 1, wn = wave & 1;
  int lrow = lane & 15, khi = lane >> 4;
  f32x4 acc[4][4];
#pragma unroll
  for (int m = 0; m < 4; ++m)
#pragma unroll
    for (int n = 0; n < 4; ++n) acc[m][n] = (f32x4){0.f, 0.f, 0.f, 0.f};

  auto compute = [&]() {
#pragma unroll
    for (int kk = 0; kk < 2; ++kk) {
      int kslot = kk * 4 + khi;
      short8 af[4], bfv[4];
#pragma unroll
      for (int m = 0; m < 4; ++m) {
        int row = wm * 64 + m * 16 + lrow;
        int slotx = kslot ^ (row & 7);
        af[m] = *(const short8*)(&ldsA[row * 64 + slotx * 8]);
      }
#pragma unroll
      for (int n = 0; n < 4; ++n) {
        int row = wn * 64 + n * 16 + lrow;
        int slotx = kslot ^ (row & 7);
        bfv[n] = *(const short8*)(&ldsB[row * 64 + slotx * 8]);
      }
#pragma unroll
      for (int m = 0; m < 4; ++m)
#pragma unroll
        for (int n = 0; n < 4; ++n)
          acc[m][n] = __builtin_amdgcn_mfma_f32_16x16x32_bf16(af[m], bfv[n], acc[m][n], 0, 0, 0);
    }
  };

  const int nk = DF / 64;
  for (int ks = 0; ks < nk; ++ks) {
    stage(ks);
    __syncthreads();
    compute();
    __syncthreads();
  }

#pragma unroll
  for (int m = 0; m < 4; ++m) {
    int rbase = wm * 64 + m * 16 + khi * 4;
#pragma unroll
    for (int j = 0; j < 4; ++j) {
      int lr = rbase + j;
      int pos = m0 + lr;
      if (pos < cnt) {
        int tok = toksh[lr];
        float wgt = wsh[lr];
#pragma unroll
        for (int n = 0; n < 4; ++n) {
          int dc = d0 + wn * 64 + n * 16 + lrow;
          atomicAdd(&out[(size_t)tok * DM + dc], wgt * acc[m][n][j]);
        }
      }
    }
  }
}

extern "C" void kernel_launch(void* const* d_in, const int* in_sizes, int n_in,
                              void* d_out, int out_size, void* d_ws, size_t ws_size,
                              hipStream_t stream) {
  const float* x  = (const float*)d_in[0];
  const float* Wg = (const float*)d_in[1];
  const float* bg = (const float*)d_in[2];
  const float* W1 = (const float*)d_in[3];
  const float* b1 = (const float*)d_in[4];
  const float* W2 = (const float*)d_in[5];
  const float* b2 = (const float*)d_in[6];
  float* out = (float*)d_out;

  uint8_t* ws = (uint8_t*)d_ws;
  size_t off = 0;
  auto alloc = [&](size_t bytes) {
    size_t o = off;
    off = (off + bytes + 255) & ~(size_t)255;
    return o;
  };
  size_t o_counts = alloc(NE * 4);
  size_t o_offsets = alloc(NE * 4);
  size_t o_work = alloc(NSLOT * 4);
  size_t o_choice = alloc((size_t)2 * T_TOK * 4);
  size_t o_wts = alloc((size_t)2 * T_TOK * 4);
  size_t o_btok = alloc((size_t)NE * T_TOK * 4);
  size_t o_bw = alloc((size_t)NE * T_TOK * 4);
  size_t o_xb = alloc((size_t)T_TOK * DM * 2);
  size_t o_w1t = alloc((size_t)NE * DF * DM * 2);
  size_t o_w2t = alloc((size_t)NE * DM * DF * 2);
  size_t o_h = alloc((size_t)2 * T_TOK * DF * 2);

  if (off > ws_size) {
    k_probe<<<dim3(1024), dim3(256), 0, stream>>>(out, (float)(double)ws_size, out_size);
    return;
  }

  int* counts = (int*)(ws + o_counts);
  int* offsets = (int*)(ws + o_offsets);
  int* work = (int*)(ws + o_work);
  int* choice2 = (int*)(ws + o_choice);
  float* wtsp = (float*)(ws + o_wts);
  int* btok = (int*)(ws + o_btok);
  float* bwp = (float*)(ws + o_bw);
  unsigned short* xb = (unsigned short*)(ws + o_xb);
  unsigned short* w1t = (unsigned short*)(ws + o_w1t);
  unsigned short* w2t = (unsigned short*)(ws + o_w2t);
  unsigned short* Hbuf = (unsigned short*)(ws + o_h);

  k_gate<<<dim3(T_TOK / 4), dim3(256), 0, stream>>>(x, xb, Wg, bg, choice2, wtsp);
  k_transpose_bf16<<<dim3(DF / 64, DM / 64, NE), dim3(256), 0, stream>>>(W1, w1t, DM, DF);
  k_transpose_bf16<<<dim3(DM / 64, DF / 64, NE), dim3(256), 0, stream>>>(W2, w2t, DF, DM);
  k_bucket<<<dim3(1), dim3(1024), 0, stream>>>(choice2, wtsp, counts, offsets, btok, bwp, work);
  k_outinit<<<dim3(T_TOK), dim3(256), 0, stream>>>(choice2, wtsp, b2, out);

  int g1x = DF / 128;  // 32
  int g2x = DM / 128;  // 8
  k_gemm1<<<dim3(g1x * NSLOT), dim3(256), 0, stream>>>(
      xb, w1t, b1, counts, offsets, btok, work, Hbuf, g1x);
  k_gemm2<<<dim3(g2x * NSLOT), dim3(256), 0, stream>>>(
      Hbuf, w2t, counts, offsets, btok, bwp, work, out, g2x);
}

// Round 14
// 578.454 us; speedup vs baseline: 1.5315x; 1.0233x over previous
//
#include <hip/hip_runtime.h>
#include <hip/hip_bf16.h>
#include <stdint.h>

#define T_TOK 8192
#define DM 1024
#define DF 4096
#define NE 8
#define NSLOT 136   // max live by-slots: 16384/128 + 8

typedef __attribute__((ext_vector_type(8))) short short8;
typedef __attribute__((ext_vector_type(8))) unsigned short ushort8;
typedef __attribute__((ext_vector_type(4))) float f32x4;

#define AS1 __attribute__((address_space(1)))
#define AS3 __attribute__((address_space(3)))

#define NB_GATE (T_TOK / 4)                    // 2048
#define NB_T1 ((DF / 64) * (DM / 64) * NE)     // 8192
#define NB_T2 ((DM / 64) * (DF / 64) * NE)     // 8192

static __device__ __forceinline__ unsigned short f2bf(float f) {
  union { float f; unsigned int u; } c; c.f = f;
  unsigned int u = c.u;
  unsigned int r = (u + 0x7FFFu + ((u >> 16) & 1u)) >> 16;
  return (unsigned short)r;
}

static __device__ __forceinline__ float gelu_tanh(float v) {
  float y = 0.7978845608028654f * (v + 0.044715f * v * v * v);
  float ay = fabsf(y);
  float e = __expf(-2.0f * ay);
  float th = (1.0f - e) / (1.0f + e);
  th = copysignf(th, y);
  return 0.5f * v * (1.0f + th);
}

__global__ void k_probe(float* out, float v, int n) {
  int i = blockIdx.x * blockDim.x + threadIdx.x;
  for (; i < n; i += gridDim.x * blockDim.x) out[i] = v;
}

// Fused prologue: [0,NB_GATE) gate+out-init; then W1 transpose; then W2.
// Independent work overlapped in one dispatch (gate = HBM-read+F64,
// transpose = pure BW) — removes serialization + launch gaps.
__global__ void k_prep(const float* __restrict__ x, unsigned short* __restrict__ xb,
                       const float* __restrict__ Wg, const float* __restrict__ bg,
                       const float* __restrict__ W1, unsigned short* __restrict__ w1t,
                       const float* __restrict__ W2, unsigned short* __restrict__ w2t,
                       const float* __restrict__ b2, float* __restrict__ out,
                       int* __restrict__ choice2, float* __restrict__ wts) {
  __shared__ float tile[64][65];
  int bid = blockIdx.x;

  if (bid < NB_GATE) {
    // ---- gating (one wave per token) + bias-weighted out init ----
    int wave = threadIdx.x >> 6, lane = threadIdx.x & 63;
    int t = bid * 4 + wave;
    const float* xr = x + (size_t)t * DM;
    unsigned short* xo = xb + (size_t)t * DM;
    double acc[NE];
#pragma unroll
    for (int e = 0; e < NE; ++e) acc[e] = 0.0;
#pragma unroll
    for (int i = 0; i < 4; ++i) {
      int d = lane * 4 + i * 256;
      float4 v = *(const float4*)(xr + d);
      ushort4 o;
      o.x = f2bf(v.x); o.y = f2bf(v.y); o.z = f2bf(v.z); o.w = f2bf(v.w);
      *(ushort4*)(xo + d) = o;
      float xv[4] = {v.x, v.y, v.z, v.w};
#pragma unroll
      for (int q = 0; q < 4; ++q) {
        const float4* wg = (const float4*)(Wg + (size_t)(d + q) * NE);
        float4 w0 = wg[0], w1 = wg[1];
        acc[0] += (double)xv[q] * w0.x; acc[1] += (double)xv[q] * w0.y;
        acc[2] += (double)xv[q] * w0.z; acc[3] += (double)xv[q] * w0.w;
        acc[4] += (double)xv[q] * w1.x; acc[5] += (double)xv[q] * w1.y;
        acc[6] += (double)xv[q] * w1.z; acc[7] += (double)xv[q] * w1.w;
      }
    }
#pragma unroll
    for (int off = 32; off; off >>= 1)
#pragma unroll
      for (int e = 0; e < NE; ++e) acc[e] += __shfl_xor(acc[e], off);
    int e1i = 0, e2i = 0;
    float w1v = 0.f, w2v = 0.f;
    if (lane == 0) {
      float lg[NE];
#pragma unroll
      for (int e = 0; e < NE; ++e) lg[e] = (float)acc[e] + bg[e];
      float m = lg[0];
#pragma unroll
      for (int e = 1; e < NE; ++e) m = fmaxf(m, lg[e]);
      float s = 0.f, p[NE];
#pragma unroll
      for (int e = 0; e < NE; ++e) { p[e] = expf(lg[e] - m); s += p[e]; }
      float inv = 1.f / s;
      int i1 = 0;
#pragma unroll
      for (int e = 1; e < NE; ++e) if (lg[e] > lg[i1]) i1 = e;
      int i2 = (i1 == 0) ? 1 : 0;
#pragma unroll
      for (int e = 0; e < NE; ++e) if (e != i1 && lg[e] > lg[i2]) i2 = e;
      e1i = i1; e2i = i2;
      w1v = p[i1] * inv; w2v = p[i2] * inv;
      choice2[2 * t] = i1;     wts[2 * t] = w1v;
      choice2[2 * t + 1] = i2; wts[2 * t + 1] = w2v;
    }
    e1i = __shfl(e1i, 0); e2i = __shfl(e2i, 0);
    w1v = __shfl(w1v, 0); w2v = __shfl(w2v, 0);
    // out[t][*] = w1v*b2[e1i][*] + w2v*b2[e2i][*]
#pragma unroll
    for (int i = 0; i < 4; ++i) {
      int d = lane * 4 + i * 256;
      float4 a = *(const float4*)(b2 + (size_t)e1i * DM + d);
      float4 b = *(const float4*)(b2 + (size_t)e2i * DM + d);
      float4 o;
      o.x = w1v * a.x + w2v * b.x; o.y = w1v * a.y + w2v * b.y;
      o.z = w1v * a.z + w2v * b.z; o.w = w1v * a.w + w2v * b.w;
      *(float4*)(out + (size_t)t * DM + d) = o;
    }
    return;
  }

  // ---- weight transpose+convert: [E][R][C] fp32 -> [E][C][R] bf16 ----
  const float* src;
  unsigned short* dst;
  int R, C, r0, c0;
  if (bid < NB_GATE + NB_T1) {
    int b2i = bid - NB_GATE;
    int e = b2i >> 10, rem = b2i & 1023;     // 1024 tiles/expert = 16r x 64c
    int byy = rem >> 6, bxx = rem & 63;
    R = DM; C = DF; r0 = byy * 64; c0 = bxx * 64;
    src = W1 + (size_t)e * DM * DF;
    dst = w1t + (size_t)e * DM * DF;
  } else {
    int b2i = bid - NB_GATE - NB_T1;
    int e = b2i >> 10, rem = b2i & 1023;     // 1024 tiles/expert = 64r x 16c
    int byy = rem >> 4, bxx = rem & 15;
    R = DF; C = DM; r0 = byy * 64; c0 = bxx * 64;
    src = W2 + (size_t)e * DF * DM;
    dst = w2t + (size_t)e * DF * DM;
  }
  int tx = threadIdx.x & 15, ty = threadIdx.x >> 4;
#pragma unroll
  for (int i = 0; i < 4; ++i) {
    int r = ty + i * 16;
    float4 v = *(const float4*)(src + (size_t)(r0 + r) * C + c0 + tx * 4);
    tile[r][tx * 4 + 0] = v.x; tile[r][tx * 4 + 1] = v.y;
    tile[r][tx * 4 + 2] = v.z; tile[r][tx * 4 + 3] = v.w;
  }
  __syncthreads();
  int tx2 = threadIdx.x & 7, ty2 = threadIdx.x >> 3;  // 8 x 32
#pragma unroll
  for (int i = 0; i < 2; ++i) {
    int c = ty2 + i * 32;
    ushort8 o;
#pragma unroll
    for (int j = 0; j < 8; ++j) o[j] = f2bf(tile[tx2 * 8 + j][c]);
    *(ushort8*)(dst + (size_t)(c0 + c) * R + r0 + tx2 * 8) = o;
  }
}

// Two-phase deterministic compaction + work-queue build. 1024 thr = 16 waves:
// wave w: expert w&7, half w>>3. No global atomics, wave-uniform flow.
__global__ void k_bucket(const int* __restrict__ choice2, const float* __restrict__ wts,
                         int* __restrict__ counts, int* __restrict__ offsets,
                         int* __restrict__ btok, float* __restrict__ bw,
                         int* __restrict__ work) {
  __shared__ int c2[16];
  int tid = threadIdx.x;
  int w = tid >> 6, lane = tid & 63;
  int e = w & 7, h = w >> 3;
  int base0 = h * T_TOK;
  unsigned long long below = (lane == 0) ? 0ull : ((1ull << lane) - 1ull);
  int cnt = 0;
  for (int i0 = 0; i0 < T_TOK; i0 += 64) {
    int ce = choice2[base0 + i0 + lane];
    cnt += (int)__popcll(__ballot(ce == e));
  }
  if (lane == 0) c2[w] = cnt;
  __syncthreads();
  if (tid == 0) {
    int s = 0;
    for (int q = 0; q < NE; ++q) {
      counts[q] = c2[q] + c2[q + 8];
      offsets[q] = s; s += counts[q];
    }
    int idx = 0;
    for (int q = 0; q < NE; ++q) {
      int nby = (counts[q] + 127) >> 7;
      for (int j = 0; j < nby; ++j) work[idx++] = (q << 20) | (j << 7);
    }
    while (idx < NSLOT) work[idx++] = -1;
  }
  __syncthreads();
  int pos = h ? c2[e] : 0;
  for (int i0 = 0; i0 < T_TOK; i0 += 64) {
    int idx = base0 + i0 + lane;
    int ce = choice2[idx];
    float wt = wts[idx];
    unsigned long long m = __ballot(ce == e);
    if (ce == e) {
      int r = (int)__popcll(m & below);
      btok[e * T_TOK + pos + r] = idx >> 1;
      bw[e * T_TOK + pos + r] = wt;
    }
    pos += (int)__popcll(m);
  }
}

// ---------------- 128x128 tile GEMMs, BK=64, 256 threads (4 waves 2Mx2N) ----
// R13 structure: work-queue grid (no dead blocks), XCD-chunked swizzle over
// live blocks, single-buffer LDS, 2-barrier K-step, hoisted stage pointers.

// GEMM1: H[slot][f] = gelu(X[tok] @ W1 + b1), bf16 out.
__global__ __launch_bounds__(256, 4) void k_gemm1(
    const unsigned short* __restrict__ xb,   // [T][DM] bf16
    const unsigned short* __restrict__ w1t,  // [E][DF][DM] bf16
    const float* __restrict__ b1,            // [E][DF]
    const int* __restrict__ counts, const int* __restrict__ offsets,
    const int* __restrict__ btok, const int* __restrict__ work,
    unsigned short* __restrict__ H,          // [2T][DF] bf16
    int gx) {
  __shared__ __align__(16) unsigned short ldsA[128 * 64];
  __shared__ __align__(16) unsigned short ldsB[128 * 64];
  __shared__ int toksh[128];

  int nwg = gx * NSLOT;
  int bid = blockIdx.x;
  int wg = (bid & 7) * (nwg >> 3) + (bid >> 3);
  int slot = wg / gx;
  int bx = wg - slot * gx;
  int pk = work[slot];
  if (pk < 0) return;
  int e = pk >> 20;
  int m0 = pk & 0xFFFFF;
  int cnt = counts[e];
  int eoff = offsets[e];
  int f0 = bx * 128;
  int tid = threadIdx.x;
  int wave = tid >> 6, lane = tid & 63;

  for (int i = tid; i < 128; i += 256) {
    int p = m0 + i; if (p >= cnt) p = cnt - 1;
    toksh[i] = btok[e * T_TOK + p];
  }
  __syncthreads();

  int slin = lane & 7, rsub = lane >> 3;
  int ksl8 = (slin ^ rsub) * 8;

  const unsigned short* srcA[4];
  const unsigned short* srcB[4];
  int ldsg[4];
#pragma unroll
  for (int j = 0; j < 4; ++j) {
    int g = j * 4 + wave;
    int m = g * 8 + rsub;
    srcA[j] = xb + (size_t)toksh[m] * DM + ksl8;
    srcB[j] = w1t + ((size_t)e * DF + f0 + m) * DM + ksl8;
    ldsg[j] = g * 512;
  }

  auto stage = [&](int ks) {
#pragma unroll
    for (int j = 0; j < 4; ++j) {
      __builtin_amdgcn_global_load_lds((const AS1 void*)(srcA[j] + (size_t)ks * 64),
                                       (AS3 void*)(&ldsA[ldsg[j]]), 16, 0, 0);
      __builtin_amdgcn_global_load_lds((const AS1 void*)(srcB[j] + (size_t)ks * 64),
                                       (AS3 void*)(&ldsB[ldsg[j]]), 16, 0, 0);
    }
  };

  int wm = wave >> 1, wn = wave & 1;
  int lrow = lane & 15, khi = lane >> 4;
  f32x4 acc[4][4];
#pragma unroll
  for (int m = 0; m < 4; ++m)
#pragma unroll
    for (int n = 0; n < 4; ++n) acc[m][n] = (f32x4){0.f, 0.f, 0.f, 0.f};

  auto compute = [&]() {
#pragma unroll
    for (int kk = 0; kk < 2; ++kk) {
      int kslot = kk * 4 + khi;
      short8 af[4], bfv[4];
#pragma unroll
      for (int m = 0; m < 4; ++m) {
        int row = wm * 64 + m * 16 + lrow;
        int slotx = kslot ^ (row & 7);
        af[m] = *(const short8*)(&ldsA[row * 64 + slotx * 8]);
      }
#pragma unroll
      for (int n = 0; n < 4; ++n) {
        int row = wn * 64 + n * 16 + lrow;
        int slotx = kslot ^ (row & 7);
        bfv[n] = *(const short8*)(&ldsB[row * 64 + slotx * 8]);
      }
#pragma unroll
      for (int m = 0; m < 4; ++m)
#pragma unroll
        for (int n = 0; n < 4; ++n)
          acc[m][n] = __builtin_amdgcn_mfma_f32_16x16x32_bf16(af[m], bfv[n], acc[m][n], 0, 0, 0);
    }
  };

  const int nk = DM / 64;
  for (int ks = 0; ks < nk; ++ks) {
    stage(ks);
    __syncthreads();
    compute();
    __syncthreads();
  }

#pragma unroll
  for (int m = 0; m < 4; ++m) {
    int rbase = wm * 64 + m * 16 + khi * 4;
#pragma unroll
    for (int j = 0; j < 4; ++j) {
      int pos = m0 + rbase + j;
      if (pos < cnt) {
        size_t hrow = (size_t)(eoff + pos) * DF;
#pragma unroll
        for (int n = 0; n < 4; ++n) {
          int fl = f0 + wn * 64 + n * 16 + lrow;
          float v = acc[m][n][j] + b1[e * DF + fl];
          H[hrow + fl] = f2bf(gelu_tanh(v));
        }
      }
    }
  }
}

// GEMM2: out[tok][d] += w * (H[slot] @ W2)   (bias pre-applied by k_prep)
__global__ __launch_bounds__(256, 4) void k_gemm2(
    const unsigned short* __restrict__ H,    // [2T][DF] bf16
    const unsigned short* __restrict__ w2t,  // [E][DM][DF] bf16
    const int* __restrict__ counts, const int* __restrict__ offsets,
    const int* __restrict__ btok, const float* __restrict__ bw,
    const int* __restrict__ work,
    float* __restrict__ out, int gx) {
  __shared__ __align__(16) unsigned short ldsA[128 * 64];
  __shared__ __align__(16) unsigned short ldsB[128 * 64];
  __shared__ int toksh[128];
  __shared__ float wsh[128];

  int nwg = gx * NSLOT;
  int bid = blockIdx.x;
  int wg = (bid & 7) * (nwg >> 3) + (bid >> 3);
  int slot = wg / gx;
  int bx = wg - slot * gx;
  int pk = work[slot];
  if (pk < 0) return;
  int e = pk >> 20;
  int m0 = pk & 0xFFFFF;
  int cnt = counts[e];
  int eoff = offsets[e];
  int d0 = bx * 128;
  int tid = threadIdx.x;
  int wave = tid >> 6, lane = tid & 63;

  for (int i = tid; i < 128; i += 256) {
    int p = m0 + i; if (p >= cnt) p = cnt - 1;
    toksh[i] = btok[e * T_TOK + p];
    wsh[i] = bw[e * T_TOK + p];
  }
  __syncthreads();

  int slin = lane & 7, rsub = lane >> 3;
  int ksl8 = (slin ^ rsub) * 8;

  const unsigned short* srcA[4];
  const unsigned short* srcB[4];
  int ldsg[4];
#pragma unroll
  for (int j = 0; j < 4; ++j) {
    int g = j * 4 + wave;
    int m = g * 8 + rsub;
    int p = m0 + m; if (p >= cnt) p = cnt - 1;
    srcA[j] = H + (size_t)(eoff + p) * DF + ksl8;
    srcB[j] = w2t + ((size_t)e * DM + d0 + m) * DF + ksl8;
    ldsg[j] = g * 512;
  }

  auto stage = [&](int ks) {
#pragma unroll
    for (int j = 0; j < 4; ++j) {
      __builtin_amdgcn_global_load_lds((const AS1 void*)(srcA[j] + (size_t)ks * 64),
                                       (AS3 void*)(&ldsA[ldsg[j]]), 16, 0, 0);
      __builtin_amdgcn_global_load_lds((const AS1 void*)(srcB[j] + (size_t)ks * 64),
                                       (AS3 void*)(&ldsB[ldsg[j]]), 16, 0, 0);
    }
  };

  int wm = wave >> 1, wn = wave & 1;
  int lrow = lane & 15, khi = lane >> 4;
  f32x4 acc[4][4];
#pragma unroll
  for (int m = 0; m < 4; ++m)
#pragma unroll
    for (int n = 0; n < 4; ++n) acc[m][n] = (f32x4){0.f, 0.f, 0.f, 0.f};

  auto compute = [&]() {
#pragma unroll
    for (int kk = 0; kk < 2; ++kk) {
      int kslot = kk * 4 + khi;
      short8 af[4], bfv[4];
#pragma unroll
      for (int m = 0; m < 4; ++m) {
        int row = wm * 64 + m * 16 + lrow;
        int slotx = kslot ^ (row & 7);
        af[m] = *(const short8*)(&ldsA[row * 64 + slotx * 8]);
      }
#pragma unroll
      for (int n = 0; n < 4; ++n) {
        int row = wn * 64 + n * 16 + lrow;
        int slotx = kslot ^ (row & 7);
        bfv[n] = *(const short8*)(&ldsB[row * 64 + slotx * 8]);
      }
#pragma unroll
      for (int m = 0; m < 4; ++m)
#pragma unroll
        for (int n = 0; n < 4; ++n)
          acc[m][n] = __builtin_amdgcn_mfma_f32_16x16x32_bf16(af[m], bfv[n], acc[m][n], 0, 0, 0);
    }
  };

  const int nk = DF / 64;
  for (int ks = 0; ks < nk; ++ks) {
    stage(ks);
    __syncthreads();
    compute();
    __syncthreads();
  }

#pragma unroll
  for (int m = 0; m < 4; ++m) {
    int rbase = wm * 64 + m * 16 + khi * 4;
#pragma unroll
    for (int j = 0; j < 4; ++j) {
      int lr = rbase + j;
      int pos = m0 + lr;
      if (pos < cnt) {
        int tok = toksh[lr];
        float wgt = wsh[lr];
#pragma unroll
        for (int n = 0; n < 4; ++n) {
          int dc = d0 + wn * 64 + n * 16 + lrow;
          atomicAdd(&out[(size_t)tok * DM + dc], wgt * acc[m][n][j]);
        }
      }
    }
  }
}

extern "C" void kernel_launch(void* const* d_in, const int* in_sizes, int n_in,
                              void* d_out, int out_size, void* d_ws, size_t ws_size,
                              hipStream_t stream) {
  const float* x  = (const float*)d_in[0];
  const float* Wg = (const float*)d_in[1];
  const float* bg = (const float*)d_in[2];
  const float* W1 = (const float*)d_in[3];
  const float* b1 = (const float*)d_in[4];
  const float* W2 = (const float*)d_in[5];
  const float* b2 = (const float*)d_in[6];
  float* out = (float*)d_out;

  uint8_t* ws = (uint8_t*)d_ws;
  size_t off = 0;
  auto alloc = [&](size_t bytes) {
    size_t o = off;
    off = (off + bytes + 255) & ~(size_t)255;
    return o;
  };
  size_t o_counts = alloc(NE * 4);
  size_t o_offsets = alloc(NE * 4);
  size_t o_work = alloc(NSLOT * 4);
  size_t o_choice = alloc((size_t)2 * T_TOK * 4);
  size_t o_wts = alloc((size_t)2 * T_TOK * 4);
  size_t o_btok = alloc((size_t)NE * T_TOK * 4);
  size_t o_bw = alloc((size_t)NE * T_TOK * 4);
  size_t o_xb = alloc((size_t)T_TOK * DM * 2);
  size_t o_w1t = alloc((size_t)NE * DF * DM * 2);
  size_t o_w2t = alloc((size_t)NE * DM * DF * 2);
  size_t o_h = alloc((size_t)2 * T_TOK * DF * 2);

  if (off > ws_size) {
    k_probe<<<dim3(1024), dim3(256), 0, stream>>>(out, (float)(double)ws_size, out_size);
    return;
  }

  int* counts = (int*)(ws + o_counts);
  int* offsets = (int*)(ws + o_offsets);
  int* work = (int*)(ws + o_work);
  int* choice2 = (int*)(ws + o_choice);
  float* wtsp = (float*)(ws + o_wts);
  int* btok = (int*)(ws + o_btok);
  float* bwp = (float*)(ws + o_bw);
  unsigned short* xb = (unsigned short*)(ws + o_xb);
  unsigned short* w1t = (unsigned short*)(ws + o_w1t);
  unsigned short* w2t = (unsigned short*)(ws + o_w2t);
  unsigned short* Hbuf = (unsigned short*)(ws + o_h);

  k_prep<<<dim3(NB_GATE + NB_T1 + NB_T2), dim3(256), 0, stream>>>(
      x, xb, Wg, bg, W1, w1t, W2, w2t, b2, out, choice2, wtsp);
  k_bucket<<<dim3(1), dim3(1024), 0, stream>>>(choice2, wtsp, counts, offsets, btok, bwp, work);

  int g1x = DF / 128;  // 32
  int g2x = DM / 128;  // 8
  k_gemm1<<<dim3(g1x * NSLOT), dim3(256), 0, stream>>>(
      xb, w1t, b1, counts, offsets, btok, work, Hbuf, g1x);
  k_gemm2<<<dim3(g2x * NSLOT), dim3(256), 0, stream>>>(
      Hbuf, w2t, counts, offsets, btok, bwp, work, out, g2x);
}